// Round 1
// baseline (214.658 us; speedup 1.0000x reference)
//
#include <hip/hip_runtime.h>

typedef short short8 __attribute__((ext_vector_type(8)));
typedef short s4v __attribute__((ext_vector_type(4)));
typedef float floatx4 __attribute__((ext_vector_type(4)));

#define BB 4
#define CC 124
#define CP 128
#define NN 4096
#define NSPLIT 4
#define KSPLIT (NN / NSPLIT)   // 1024 keys per split
#define TN 64                  // keys per chunk
#define NCHUNK (KSPLIT / TN)   // 16

// float -> bf16 bits, round-to-nearest-even (inputs here are never NaN)
static __device__ __forceinline__ unsigned short f2bf(float f) {
    unsigned int u = __float_as_uint(f);
    u += 0x7fffu + ((u >> 16) & 1u);
    return (unsigned short)(u >> 16);
}

// ---------------------------------------------------------------------------
// Step A: Bf[b,o,n] = sum_c Wb[o,c] * x[b,c,n], written as bf16 in TWO layouts:
//   rows[b][n][CP]  (Q and K operand reads: contiguous along c)
//   cols[b][CP][NN] (V operand reads: contiguous along n)
// Pad channels 124..127 are zero in both (required: they enter the MFMA K-dim).
// ---------------------------------------------------------------------------
__global__ __launch_bounds__(256) void bf_proj_kernel(const float* __restrict__ x,
                                                      const float* __restrict__ Wb,
                                                      unsigned short* __restrict__ rows,
                                                      unsigned short* __restrict__ cols) {
    __shared__ float xs[CC][68];            // 64-wide n tile, pad->68 (16B-aligned rows)
    __shared__ float wsh[CP][CC];           // Wb staged, rows 124..127 zeroed
    __shared__ unsigned short ts[64][CP];   // transpose staging for `rows` write
    const int tid = threadIdx.x;
    const int b = blockIdx.y;
    const int n0 = blockIdx.x * 64;
    const float* xb = x + (size_t)b * CC * NN + n0;
    for (int i = tid; i < CC * 64; i += 256) {
        int c = i >> 6, n = i & 63;
        xs[c][n] = xb[(size_t)c * NN + n];
    }
    for (int i = tid; i < CC * CC; i += 256) wsh[i / CC][i % CC] = Wb[i];
    for (int i = tid; i < 4 * CC; i += 256) wsh[CC + i / CC][i % CC] = 0.0f;
    __syncthreads();
    // register blocking: each thread computes 8 o x 4 n
    const int og = tid >> 4;         // 0..15 -> o0 = og*8 (covers 0..127)
    const int n4 = (tid & 15) * 4;   // 0..60
    const int o0 = og * 8;
    float acc[8][4];
#pragma unroll
    for (int k = 0; k < 8; ++k)
#pragma unroll
        for (int j = 0; j < 4; ++j) acc[k][j] = 0.f;
    for (int c = 0; c < CC; ++c) {
        floatx4 xv = *(const floatx4*)&xs[c][n4];
#pragma unroll
        for (int k = 0; k < 8; ++k) {
            float wv = wsh[o0 + k][c];
            acc[k][0] += wv * xv[0];
            acc[k][1] += wv * xv[1];
            acc[k][2] += wv * xv[2];
            acc[k][3] += wv * xv[3];
        }
    }
    unsigned short* colb = cols + (size_t)b * CP * NN + n0;
#pragma unroll
    for (int k = 0; k < 8; ++k) {
#pragma unroll
        for (int j = 0; j < 4; ++j) {
            unsigned short v = f2bf(acc[k][j]);
            ts[n4 + j][o0 + k] = v;
            colb[(size_t)(o0 + k) * NN + n4 + j] = v;
        }
    }
    __syncthreads();
    unsigned short* rowb = rows + ((size_t)b * NN + n0) * CP;
    const unsigned short* tsf = &ts[0][0];
    for (int i = tid; i < (64 * CP) / 4; i += 256)
        ((s4v*)rowb)[i] = ((const s4v*)tsf)[i];
}

// ---------------------------------------------------------------------------
// Flash attention with Q=K=V, key-split x4, 32 query rows per wave.
// No __syncthreads in the hot loop: P roundtrip uses per-wave-private LDS
// ordered with s_waitcnt lgkmcnt(0). Softmax stats kept in base-2 units.
// Outputs unnormalized O_partial [split][b][m][CP] fp32 plus (m,l) per row.
// ---------------------------------------------------------------------------
__global__ __launch_bounds__(256, 2) void attn_kernel(const unsigned short* __restrict__ rows,
                                                      const unsigned short* __restrict__ cols,
                                                      float* __restrict__ opart,
                                                      float* __restrict__ ml) {
    __shared__ unsigned short pl[4][32][72];  // per-wave private P tile (pad 64->72)
    // remap so co-resident blocks (id, id+256) share (b, split) -> shared L1 key stream
    const int id = blockIdx.x;
    const int grp = id & 15;
    const int b = grp & 3;
    const int split = grp >> 2;
    const int mtile = id >> 4;            // 0..31
    const int wave = threadIdx.x >> 6;
    const int lane = threadIdx.x & 63;
    const int col = lane & 15;
    const int quad = lane >> 4;
    const int m0 = mtile * 128 + wave * 32;
    const unsigned short* rb = rows + (size_t)b * NN * CP;
    const unsigned short* cb = cols + (size_t)b * CP * NN;
    const floatx4 fzero = {0.f, 0.f, 0.f, 0.f};
    const float L2E = 1.44269504088896340736f;

    // Q A-frags, resident in registers for the whole kernel
    short8 qf[2][4];
#pragma unroll
    for (int ms = 0; ms < 2; ++ms) {
        const unsigned short* qrow = rb + (size_t)(m0 + ms * 16 + col) * CP + quad * 8;
#pragma unroll
        for (int t = 0; t < 4; ++t) qf[ms][t] = *(const short8*)(qrow + t * 32);
    }

    floatx4 oacc[2][8];
#pragma unroll
    for (int ms = 0; ms < 2; ++ms)
#pragma unroll
        for (int s8 = 0; s8 < 8; ++s8) oacc[ms][s8] = fzero;
    float mrow[2][4], lrow[2][4];
#pragma unroll
    for (int ms = 0; ms < 2; ++ms)
#pragma unroll
        for (int r = 0; r < 4; ++r) { mrow[ms][r] = -1e30f; lrow[ms][r] = 0.f; }

    unsigned short (*pw)[72] = pl[wave];

    for (int ch = 0; ch < NCHUNK; ++ch) {
        const int n0 = split * KSPLIT + ch * TN;
        // ---- S = Q K^T over this 64-key chunk ----
        floatx4 sacc[2][4];
#pragma unroll
        for (int ms = 0; ms < 2; ++ms)
#pragma unroll
            for (int u = 0; u < 4; ++u) sacc[ms][u] = fzero;
#pragma unroll
        for (int t = 0; t < 4; ++t) {
#pragma unroll
            for (int u = 0; u < 4; ++u) {
                short8 kf = *(const short8*)(rb + (size_t)(n0 + u * 16 + col) * CP + t * 32 + quad * 8);
                sacc[0][u] = __builtin_amdgcn_mfma_f32_16x16x32_bf16(qf[0][t], kf, sacc[0][u], 0, 0, 0);
                sacc[1][u] = __builtin_amdgcn_mfma_f32_16x16x32_bf16(qf[1][t], kf, sacc[1][u], 0, 0, 0);
            }
        }
        // ---- online softmax (lane owns rows quad*4+r of each 16-row subtile) ----
        float alpha[2][4];
#pragma unroll
        for (int ms = 0; ms < 2; ++ms) {
#pragma unroll
            for (int r = 0; r < 4; ++r) {
                float sm = fmaxf(fmaxf(sacc[ms][0][r], sacc[ms][1][r]),
                                 fmaxf(sacc[ms][2][r], sacc[ms][3][r])) * L2E;
                sm = fmaxf(sm, __shfl_xor(sm, 1));
                sm = fmaxf(sm, __shfl_xor(sm, 2));
                sm = fmaxf(sm, __shfl_xor(sm, 4));
                sm = fmaxf(sm, __shfl_xor(sm, 8));
                float mn = fmaxf(mrow[ms][r], sm);
                alpha[ms][r] = exp2f(mrow[ms][r] - mn);
                mrow[ms][r] = mn;
                float psum = 0.f;
#pragma unroll
                for (int u = 0; u < 4; ++u) {
                    float p = exp2f(sacc[ms][u][r] * L2E - mn);
                    pw[ms * 16 + quad * 4 + r][u * 16 + col] = f2bf(p);
                    psum += p;
                }
                psum += __shfl_xor(psum, 1);
                psum += __shfl_xor(psum, 2);
                psum += __shfl_xor(psum, 4);
                psum += __shfl_xor(psum, 8);
                lrow[ms][r] = lrow[ms][r] * alpha[ms][r] + psum;
            }
        }
        // rescale O only when some row's max moved (wave-uniform branch)
        int need = 0;
#pragma unroll
        for (int ms = 0; ms < 2; ++ms)
#pragma unroll
            for (int r = 0; r < 4; ++r) need |= (alpha[ms][r] < 1.f);
        if (__ballot(need) != 0ull) {
#pragma unroll
            for (int ms = 0; ms < 2; ++ms)
#pragma unroll
                for (int s8 = 0; s8 < 8; ++s8)
#pragma unroll
                    for (int r = 0; r < 4; ++r) oacc[ms][s8][r] *= alpha[ms][r];
        }
        // drain LDS writes (cross-lane, within-wave visibility; no barrier needed)
        asm volatile("s_waitcnt lgkmcnt(0)" ::: "memory");
        // ---- O += P V ----
#pragma unroll
        for (int u2 = 0; u2 < 2; ++u2) {
            short8 af0 = *(const short8*)&pw[col][u2 * 32 + quad * 8];
            short8 af1 = *(const short8*)&pw[16 + col][u2 * 32 + quad * 8];
#pragma unroll
            for (int s8 = 0; s8 < 8; ++s8) {
                short8 vf = *(const short8*)(cb + (size_t)(s8 * 16 + col) * NN + n0 + u2 * 32 + quad * 8);
                oacc[0][s8] = __builtin_amdgcn_mfma_f32_16x16x32_bf16(af0, vf, oacc[0][s8], 0, 0, 0);
                oacc[1][s8] = __builtin_amdgcn_mfma_f32_16x16x32_bf16(af1, vf, oacc[1][s8], 0, 0, 0);
            }
        }
    }
    // ---- epilogue: unnormalized partials + per-row (m, l) ----
    float* ob = opart + (size_t)(split * BB + b) * NN * CP;
#pragma unroll
    for (int ms = 0; ms < 2; ++ms)
#pragma unroll
        for (int s8 = 0; s8 < 8; ++s8)
#pragma unroll
            for (int r = 0; r < 4; ++r)
                ob[(size_t)(m0 + ms * 16 + quad * 4 + r) * CP + s8 * 16 + col] = oacc[ms][s8][r];
    if (col == 0) {
        float* mlb = ml + (size_t)(split * BB + b) * NN * 2;
#pragma unroll
        for (int ms = 0; ms < 2; ++ms)
#pragma unroll
            for (int r = 0; r < 4; ++r) {
                int m = m0 + ms * 16 + quad * 4 + r;
                mlb[m * 2] = mrow[ms][r];
                mlb[m * 2 + 1] = lrow[ms][r];
            }
    }
}

// ---------------------------------------------------------------------------
// Combine the 4 key-split partials, normalize, fuse gamma*E + x, write [b][c][m].
// ---------------------------------------------------------------------------
__global__ __launch_bounds__(256) void combine_kernel(const float* __restrict__ opart,
                                                      const float* __restrict__ ml,
                                                      const float* __restrict__ x,
                                                      const float* __restrict__ gamma,
                                                      float* __restrict__ out) {
    const int tid = threadIdx.x;
    const int ty = tid >> 5, tx = tid & 31;
    if (tx >= 31) return;                 // 124 = 31 * 4 channels
    const int b = blockIdx.y;
    const int m = blockIdx.x * 8 + ty;
    const int c0 = tx * 4;
    float mv[NSPLIT], lv[NSPLIT];
    float M = -1e30f;
#pragma unroll
    for (int s = 0; s < NSPLIT; ++s) {
        const float* p = ml + ((size_t)(s * BB + b) * NN + m) * 2;
        mv[s] = p[0];
        lv[s] = p[1];
        M = fmaxf(M, mv[s]);
    }
    float L = 0.f;
    floatx4 acc = {0.f, 0.f, 0.f, 0.f};
#pragma unroll
    for (int s = 0; s < NSPLIT; ++s) {
        float w = exp2f(mv[s] - M);
        L += w * lv[s];
        floatx4 o = *(const floatx4*)(opart + ((size_t)(s * BB + b) * NN + m) * CP + c0);
        acc += o * w;
    }
    const float g = gamma[0] / L;
#pragma unroll
    for (int j = 0; j < 4; ++j) {
        size_t idx = ((size_t)b * CC + c0 + j) * NN + m;
        out[idx] = acc[j] * g + x[idx];
    }
}

extern "C" void kernel_launch(void* const* d_in, const int* in_sizes, int n_in,
                              void* d_out, int out_size, void* d_ws, size_t ws_size,
                              hipStream_t stream) {
    const float* x = (const float*)d_in[0];
    const float* Wb = (const float*)d_in[1];
    const float* gamma = (const float*)d_in[2];
    float* out = (float*)d_out;

    const size_t rows_b = (size_t)BB * NN * CP * sizeof(unsigned short);   // 4 MB
    const size_t cols_b = rows_b;                                          // 4 MB
    const size_t opart_b = (size_t)NSPLIT * BB * NN * CP * sizeof(float);  // 32 MB
    const size_t ml_b = (size_t)NSPLIT * BB * NN * 2 * sizeof(float);      // 0.5 MB
    if (ws_size < rows_b + cols_b + opart_b + ml_b) return;  // fail visibly, don't corrupt

    char* w = (char*)d_ws;
    unsigned short* rows = (unsigned short*)w;
    unsigned short* cols = (unsigned short*)(w + rows_b);
    float* opart = (float*)(w + rows_b + cols_b);
    float* ml = (float*)(w + rows_b + cols_b + opart_b);

    bf_proj_kernel<<<dim3(NN / 64, BB), 256, 0, stream>>>(x, Wb, rows, cols);
    attn_kernel<<<dim3(512), 256, 0, stream>>>(rows, cols, opart, ml);
    combine_kernel<<<dim3(NN / 8, BB), 256, 0, stream>>>(opart, ml, x, gamma, out);
}